// Round 4
// baseline (450.550 us; speedup 1.0000x reference)
//
#include <hip/hip_runtime.h>
#include <math.h>

#define HDIM   768
#define NSAMP  512
#define NLOG   513            // 1 target + 512 noise
#define VOCAB  50257

// ---------------------------------------------------------------------------
// Sorted-gather pipeline:
//  A) zero histogram counts
//  B) histogram of all 525312 vocab indices
//  C) single-block exclusive prefix sum over 50257 bins -> cursor
//  D) scatter: counting sort of (vocab, payload) pairs
//  E) gather-dot: ONE LANE PER OCCURRENCE. Lane streams its W row (mostly
//     shared with neighbors -> same-address broadcast) and its h row
//     (L2-resident, 3 MB) through 4 independent accumulators. No shuffles,
//     no branches, no loop-carried deps -> max memory-level parallelism.
//  F) per-token log-softmax + smoothed loss
//  G) deterministic mean
// ---------------------------------------------------------------------------

__global__ __launch_bounds__(256) void zero_kernel(unsigned int* __restrict__ p, int n)
{
    int i = blockIdx.x * 256 + threadIdx.x;
    int stride = gridDim.x * 256;
    for (; i < n; i += stride) p[i] = 0u;
}

__global__ __launch_bounds__(256) void hist_kernel(
    const int* __restrict__ target, const int* __restrict__ noise,
    unsigned int* __restrict__ counts, int N)
{
    int i = blockIdx.x * 256 + threadIdx.x;
    int stride = gridDim.x * 256;
    const int nn4 = (N * NSAMP) / 4;
    const int4* noise4 = reinterpret_cast<const int4*>(noise);
    for (int k = i; k < nn4; k += stride) {
        const int4 v = noise4[k];
        atomicAdd(&counts[v.x], 1u);
        atomicAdd(&counts[v.y], 1u);
        atomicAdd(&counts[v.z], 1u);
        atomicAdd(&counts[v.w], 1u);
    }
    for (int k = i; k < N; k += stride) atomicAdd(&counts[target[k]], 1u);
}

// single block, 1024 threads, chunked Hillis-Steele scan
__global__ __launch_bounds__(1024) void scan_kernel(
    const unsigned int* __restrict__ counts, unsigned int* __restrict__ cursor)
{
    const int tid = threadIdx.x;
    const int CH  = (VOCAB + 1023) / 1024;       // 50
    const int lo  = tid * CH;
    const int hi  = (lo + CH < VOCAB) ? lo + CH : VOCAB;

    __shared__ unsigned int lds[1024];
    unsigned int s = 0;
    for (int i = lo; i < hi; ++i) s += counts[i];
    lds[tid] = s;
    __syncthreads();
    for (int off = 1; off < 1024; off <<= 1) {
        unsigned int t = (tid >= off) ? lds[tid - off] : 0u;
        __syncthreads();
        lds[tid] += t;
        __syncthreads();
    }
    unsigned int run = (tid > 0) ? lds[tid - 1] : 0u;   // exclusive prefix
    for (int i = lo; i < hi; ++i) { cursor[i] = run; run += counts[i]; }
}

__global__ __launch_bounds__(256) void scatter_kernel(
    const int* __restrict__ target, const int* __restrict__ noise,
    unsigned int* __restrict__ cursor,
    unsigned int* __restrict__ sorted_v, unsigned int* __restrict__ sorted_pay, int N)
{
    int i = blockIdx.x * 256 + threadIdx.x;
    int stride = gridDim.x * 256;
    const int nn4 = (N * NSAMP) / 4;
    const int4* noise4 = reinterpret_cast<const int4*>(noise);
    for (int k = i; k < nn4; k += stride) {
        const int4 vv = reinterpret_cast<const int4*>(noise4)[k];
        const int kk = k * 4;
        #pragma unroll
        for (int j = 0; j < 4; ++j) {
            const int v    = (j == 0) ? vv.x : (j == 1) ? vv.y : (j == 2) ? vv.z : vv.w;
            const int idx  = kk + j;
            const int tok  = idx >> 9;            // /512
            const int slot = (idx & 511) + 1;     // noise -> slots 1..512
            const unsigned int pos = atomicAdd(&cursor[v], 1u);
            sorted_v[pos]   = (unsigned int)v;
            sorted_pay[pos] = ((unsigned int)tok << 10) | (unsigned int)slot;
        }
    }
    for (int k = i; k < N; k += stride) {
        const int v = target[k];
        const unsigned int pos = atomicAdd(&cursor[v], 1u);
        sorted_v[pos]   = (unsigned int)v;
        sorted_pay[pos] = ((unsigned int)k << 10);   // slot 0
    }
}

#define GTPB 256
__global__ __launch_bounds__(GTPB) void gather_dot_kernel(
    const float* __restrict__ h, const float* __restrict__ W,
    const unsigned int* __restrict__ sorted_v,
    const unsigned int* __restrict__ sorted_pay,
    float* __restrict__ logits, int nocc)
{
    const int i = blockIdx.x * GTPB + threadIdx.x;
    if (i >= nocc) return;

    const int v    = (int)sorted_v[i];
    const int p    = (int)sorted_pay[i];
    const int tok  = p >> 10;
    const int slot = p & 1023;

    const float4* __restrict__ wr = reinterpret_cast<const float4*>(W + (size_t)v   * HDIM);
    const float4* __restrict__ hr = reinterpret_cast<const float4*>(h + (size_t)tok * HDIM);

    float a0 = 0.f, a1 = 0.f, a2 = 0.f, a3 = 0.f;
    #pragma unroll 4
    for (int k = 0; k < HDIM / 4; k += 4) {
        const float4 w0 = wr[k + 0], w1 = wr[k + 1], w2 = wr[k + 2], w3 = wr[k + 3];
        const float4 x0 = hr[k + 0], x1 = hr[k + 1], x2 = hr[k + 2], x3 = hr[k + 3];
        a0 += w0.x * x0.x + w0.y * x0.y + w0.z * x0.z + w0.w * x0.w;
        a1 += w1.x * x1.x + w1.y * x1.y + w1.z * x1.z + w1.w * x1.w;
        a2 += w2.x * x2.x + w2.y * x2.y + w2.z * x2.z + w2.w * x2.w;
        a3 += w3.x * x3.x + w3.y * x3.y + w3.z * x3.z + w3.w * x3.w;
    }
    logits[(size_t)tok * NLOG + slot] = (a0 + a1) + (a2 + a3);
}

__global__ __launch_bounds__(256) void softmax_loss_kernel(
    const float* __restrict__ logits, float* __restrict__ loss_per_token)
{
    const int n    = blockIdx.x;
    const int tid  = threadIdx.x;
    const int lane = tid & 63;
    const int wave = tid >> 6;
    const float* row = logits + (size_t)n * NLOG;

    __shared__ float red[4];
    __shared__ float red2[4][2];

    float lmax = -INFINITY;
    for (int r = tid; r < NLOG; r += 256) lmax = fmaxf(lmax, row[r]);
    #pragma unroll
    for (int off = 32; off; off >>= 1) lmax = fmaxf(lmax, __shfl_xor(lmax, off, 64));
    if (lane == 0) red[wave] = lmax;
    __syncthreads();
    lmax = fmaxf(fmaxf(red[0], red[1]), fmaxf(red[2], red[3]));

    float esum = 0.f, lsum = 0.f;
    for (int r = tid; r < NLOG; r += 256) {
        const float l = row[r];
        esum += __expf(l - lmax);
        if (r > 0) lsum += l;
    }
    #pragma unroll
    for (int off = 32; off; off >>= 1) {
        esum += __shfl_xor(esum, off, 64);
        lsum += __shfl_xor(lsum, off, 64);
    }
    if (lane == 0) { red2[wave][0] = esum; red2[wave][1] = lsum; }
    __syncthreads();

    if (tid == 0) {
        esum = red2[0][0] + red2[1][0] + red2[2][0] + red2[3][0];
        lsum = red2[0][1] + red2[1][1] + red2[2][1] + red2[3][1];
        const float lse  = lmax + logf(esum);
        const float l0   = row[0];
        const float loss = -0.9f * (l0 - lse)
                         - (0.1f / 512.f) * (lsum - 512.f * lse);
        loss_per_token[n] = loss;
    }
}

__global__ __launch_bounds__(256) void reduce_mean_kernel(
    const float* __restrict__ x, float* __restrict__ out, int n)
{
    const int tid = threadIdx.x;
    float s = 0.f;
    for (int i = tid; i < n; i += 256) s += x[i];
    #pragma unroll
    for (int off = 32; off; off >>= 1) s += __shfl_xor(s, off, 64);
    __shared__ float red[4];
    if ((tid & 63) == 0) red[tid >> 6] = s;
    __syncthreads();
    if (tid == 0) out[0] = (red[0] + red[1] + red[2] + red[3]) / (float)n;
}

// ------------------------- legacy fallback (R1) ----------------------------
__global__ __launch_bounds__(512) void nce_token_kernel(
    const float* __restrict__ h, const float* __restrict__ W,
    const int* __restrict__ target, const int* __restrict__ noise,
    float* __restrict__ loss_per_token)
{
    const int n    = blockIdx.x;
    const int tid  = threadIdx.x;
    const int lane = tid & 63;
    const int wave = tid >> 6;

    __shared__ float  logits[NLOG];
    __shared__ float4 hsm[HDIM / 4];
    __shared__ float  red[8];
    __shared__ float  red2[8][2];

    const float4* hrow = reinterpret_cast<const float4*>(h + (size_t)n * HDIM);
    if (tid < HDIM / 4) hsm[tid] = hrow[tid];
    __syncthreads();

    const float4 h0 = hsm[lane];
    const float4 h1 = hsm[lane + 64];
    const float4 h2 = hsm[lane + 128];
    const int* nrow = noise + (size_t)n * NSAMP;

    for (int r = wave; r < NLOG; r += 8) {
        const int row = (r == 0) ? target[n] : nrow[r - 1];
        const float4* wr = reinterpret_cast<const float4*>(W + (size_t)row * HDIM);
        const float4 w0 = wr[lane];
        const float4 w1 = wr[lane + 64];
        const float4 w2 = wr[lane + 128];
        float s;
        s  = h0.x * w0.x + h0.y * w0.y + h0.z * w0.z + h0.w * w0.w;
        s += h1.x * w1.x + h1.y * w1.y + h1.z * w1.z + h1.w * w1.w;
        s += h2.x * w2.x + h2.y * w2.y + h2.z * w2.z + h2.w * w2.w;
        #pragma unroll
        for (int off = 32; off; off >>= 1) s += __shfl_xor(s, off, 64);
        if (lane == 0) logits[r] = s;
    }
    __syncthreads();

    float lmax = -INFINITY;
    for (int r = tid; r < NLOG; r += 512) lmax = fmaxf(lmax, logits[r]);
    #pragma unroll
    for (int off = 32; off; off >>= 1) lmax = fmaxf(lmax, __shfl_xor(lmax, off, 64));
    if (lane == 0) red[wave] = lmax;
    __syncthreads();
    if (wave == 0) {
        float m = (lane < 8) ? red[lane] : -INFINITY;
        #pragma unroll
        for (int off = 4; off; off >>= 1) m = fmaxf(m, __shfl_xor(m, off, 64));
        if (lane == 0) red[0] = m;
    }
    __syncthreads();
    lmax = red[0];

    float esum = 0.f, lsum = 0.f;
    for (int r = tid; r < NLOG; r += 512) {
        const float l = logits[r];
        esum += __expf(l - lmax);
        if (r > 0) lsum += l;
    }
    #pragma unroll
    for (int off = 32; off; off >>= 1) {
        esum += __shfl_xor(esum, off, 64);
        lsum += __shfl_xor(lsum, off, 64);
    }
    if (lane == 0) { red2[wave][0] = esum; red2[wave][1] = lsum; }
    __syncthreads();

    if (tid == 0) {
        esum = 0.f; lsum = 0.f;
        #pragma unroll
        for (int w = 0; w < 8; ++w) { esum += red2[w][0]; lsum += red2[w][1]; }
        const float lse  = lmax + logf(esum);
        const float loss = -0.9f * (logits[0] - lse)
                         - (0.1f / 512.f) * (lsum - 512.f * lse);
        loss_per_token[n] = loss;
    }
}
// ---------------------------------------------------------------------------

extern "C" void kernel_launch(void* const* d_in, const int* in_sizes, int n_in,
                              void* d_out, int out_size, void* d_ws, size_t ws_size,
                              hipStream_t stream)
{
    const float* h      = (const float*)d_in[0];   // [N, 768] fp32
    const float* W      = (const float*)d_in[1];   // [50257, 768] fp32
    const int*   target = (const int*)d_in[2];     // [N] int32
    const int*   noise  = (const int*)d_in[3];     // [N, 512] int32
    float*       out    = (float*)d_out;
    const int    N      = in_sizes[2];             // 1024 tokens
    const int    nocc   = N * NLOG;                // 525312

    // ws layout (u32/f32 elements)
    unsigned int* counts     = (unsigned int*)d_ws;
    unsigned int* cursor     = counts + VOCAB;
    unsigned int* sorted_v   = cursor + VOCAB;
    unsigned int* sorted_pay = sorted_v + nocc;
    float*        logits     = (float*)(sorted_pay + nocc);
    float*        loss       = logits + nocc;
    const size_t  need_bytes = (size_t)(2 * VOCAB + 3 * nocc + N) * 4;

    if (ws_size < need_bytes) {
        // fallback: direct gather path (R1)
        float* ws = (float*)d_ws;
        nce_token_kernel<<<N, 512, 0, stream>>>(h, W, target, noise, ws);
        reduce_mean_kernel<<<1, 256, 0, stream>>>(ws, out, N);
        return;
    }

    zero_kernel<<<(VOCAB + 255) / 256, 256, 0, stream>>>(counts, VOCAB);
    hist_kernel<<<512, 256, 0, stream>>>(target, noise, counts, N);
    scan_kernel<<<1, 1024, 0, stream>>>(counts, cursor);
    scatter_kernel<<<512, 256, 0, stream>>>(target, noise, cursor,
                                            sorted_v, sorted_pay, N);
    const int gblocks = (nocc + GTPB - 1) / GTPB;
    gather_dot_kernel<<<gblocks, GTPB, 0, stream>>>(h, W, sorted_v, sorted_pay,
                                                    logits, nocc);
    softmax_loss_kernel<<<N, 256, 0, stream>>>(logits, loss);
    reduce_mean_kernel<<<1, 256, 0, stream>>>(loss, out, N);
}

// Round 5
// 179.026 us; speedup vs baseline: 2.5167x; 2.5167x over previous
//
#include <hip/hip_runtime.h>
#include <math.h>

#define HDIM   768
#define NSAMP  512
#define NLOG   513            // 1 target + 512 noise
#define VOCAB  50257
#define PADV   53248          // 1024 * 52, padded bin count for uint4 scan

// ---------------------------------------------------------------------------
// Sorted run-gather pipeline:
//  A) memsetAsync counts = 0
//  B) histogram of all 525312 vocab indices (int4 loads, global atomics)
//  C) single-block exclusive scan over padded bins (uint4 in/out) -> cursor
//  D) scatter: counting sort, payload only (tok<<10 | slot)
//  E) gather-run: ONE WAVE PER VOCAB RUN. W row loaded once into registers
//     (coalesced, kills W re-issue), then pipelined loop over occurrences:
//     prefetch next payload + next h row while reducing current dot.
//     All loads wave-coalesced (48 lines / 3KB row = minimum for fp32).
//  F) per-token log-softmax + smoothed loss
//  G) deterministic mean
// ---------------------------------------------------------------------------

__global__ __launch_bounds__(256) void hist_kernel(
    const int* __restrict__ target, const int* __restrict__ noise,
    unsigned int* __restrict__ counts, int N)
{
    int i = blockIdx.x * 256 + threadIdx.x;
    int stride = gridDim.x * 256;
    const int nn4 = (N * NSAMP) / 4;
    const int4* noise4 = reinterpret_cast<const int4*>(noise);
    for (int k = i; k < nn4; k += stride) {
        const int4 v = noise4[k];
        atomicAdd(&counts[v.x], 1u);
        atomicAdd(&counts[v.y], 1u);
        atomicAdd(&counts[v.z], 1u);
        atomicAdd(&counts[v.w], 1u);
    }
    for (int k = i; k < N; k += stride) atomicAdd(&counts[target[k]], 1u);
}

// single block, 1024 threads, 52 bins/thread, uint4 I/O. counts is padded to
// PADV and pre-zeroed, so the pad contributes 0 and unguarded uint4 is safe.
__global__ __launch_bounds__(1024) void scan_kernel(
    const unsigned int* __restrict__ counts, unsigned int* __restrict__ cursor)
{
    const int tid = threadIdx.x;
    const uint4* c4 = reinterpret_cast<const uint4*>(counts) + tid * 13;
    uint4*      o4 = reinterpret_cast<uint4*>(cursor) + tid * 13;

    __shared__ unsigned int lds[1024];
    unsigned int s = 0;
    #pragma unroll
    for (int i = 0; i < 13; ++i) {
        const uint4 c = c4[i];
        s += c.x + c.y + c.z + c.w;
    }
    lds[tid] = s;
    __syncthreads();
    #pragma unroll
    for (int off = 1; off < 1024; off <<= 1) {
        unsigned int t = (tid >= off) ? lds[tid - off] : 0u;
        __syncthreads();
        lds[tid] += t;
        __syncthreads();
    }
    unsigned int run = (tid > 0) ? lds[tid - 1] : 0u;   // exclusive prefix
    #pragma unroll
    for (int i = 0; i < 13; ++i) {
        const uint4 c = c4[i];
        uint4 o;
        o.x = run;
        o.y = o.x + c.x;
        o.z = o.y + c.y;
        o.w = o.z + c.z;
        run = o.w + c.w;
        o4[i] = o;
    }
}

__global__ __launch_bounds__(256) void scatter_kernel(
    const int* __restrict__ target, const int* __restrict__ noise,
    unsigned int* __restrict__ cursor,
    unsigned int* __restrict__ sorted_pay, int N)
{
    int i = blockIdx.x * 256 + threadIdx.x;
    int stride = gridDim.x * 256;
    const int nn4 = (N * NSAMP) / 4;
    const int4* noise4 = reinterpret_cast<const int4*>(noise);
    for (int k = i; k < nn4; k += stride) {
        const int4 vv = noise4[k];
        const int kk = k * 4;
        #pragma unroll
        for (int j = 0; j < 4; ++j) {
            const int v    = (j == 0) ? vv.x : (j == 1) ? vv.y : (j == 2) ? vv.z : vv.w;
            const int idx  = kk + j;
            const int tok  = idx >> 9;            // /512
            const int slot = (idx & 511) + 1;     // noise -> slots 1..512
            const unsigned int pos = atomicAdd(&cursor[v], 1u);
            sorted_pay[pos] = ((unsigned int)tok << 10) | (unsigned int)slot;
        }
    }
    for (int k = i; k < N; k += stride) {
        const int v = target[k];
        const unsigned int pos = atomicAdd(&cursor[v], 1u);
        sorted_pay[pos] = ((unsigned int)k << 10);   // slot 0
    }
}

// one wave per vocab run
#define GTPB 256
__global__ __launch_bounds__(GTPB) void gather_run_kernel(
    const float* __restrict__ h, const float* __restrict__ W,
    const unsigned int* __restrict__ counts,
    const unsigned int* __restrict__ cursor,      // end offsets after scatter
    const unsigned int* __restrict__ sorted_pay,
    float* __restrict__ logits)
{
    const int v = blockIdx.x * (GTPB / 64) + (threadIdx.x >> 6);
    if (v >= VOCAB) return;
    const int cnt = (int)counts[v];
    if (cnt == 0) return;
    const int start = (int)cursor[v] - cnt;
    const int lane  = threadIdx.x & 63;

    // W row resident in registers for the whole run
    const float4* wr = reinterpret_cast<const float4*>(W + (size_t)v * HDIM);
    const float4 w0 = wr[lane];
    const float4 w1 = wr[lane + 64];
    const float4 w2 = wr[lane + 128];

    // prologue: load first payload + h row
    unsigned int pay = sorted_pay[start];
    const float4* hr = reinterpret_cast<const float4*>(h + (size_t)(pay >> 10) * HDIM);
    float4 a = hr[lane], b = hr[lane + 64], c = hr[lane + 128];

    for (int j = 0; j < cnt; ++j) {
        // prefetch next payload + h row (guarded to a valid address)
        const int jn = (j + 1 < cnt) ? j + 1 : j;
        const unsigned int payn = sorted_pay[start + jn];
        const float4* hrn = reinterpret_cast<const float4*>(h + (size_t)(payn >> 10) * HDIM);
        const float4 an = hrn[lane], bn = hrn[lane + 64], cn = hrn[lane + 128];

        float s;
        s  = w0.x * a.x + w0.y * a.y + w0.z * a.z + w0.w * a.w;
        s += w1.x * b.x + w1.y * b.y + w1.z * b.z + w1.w * b.w;
        s += w2.x * c.x + w2.y * c.y + w2.z * c.z + w2.w * c.w;
        #pragma unroll
        for (int off = 32; off; off >>= 1) s += __shfl_xor(s, off, 64);
        if (lane == 0) {
            const int tok  = (int)(pay >> 10);
            const int slot = (int)(pay & 1023u);
            logits[(size_t)tok * NLOG + slot] = s;
        }
        pay = payn; a = an; b = bn; c = cn;
    }
}

__global__ __launch_bounds__(256) void softmax_loss_kernel(
    const float* __restrict__ logits, float* __restrict__ loss_per_token)
{
    const int n    = blockIdx.x;
    const int tid  = threadIdx.x;
    const int lane = tid & 63;
    const int wave = tid >> 6;
    const float* row = logits + (size_t)n * NLOG;

    __shared__ float red[4];
    __shared__ float red2[4][2];

    float lmax = -INFINITY;
    for (int r = tid; r < NLOG; r += 256) lmax = fmaxf(lmax, row[r]);
    #pragma unroll
    for (int off = 32; off; off >>= 1) lmax = fmaxf(lmax, __shfl_xor(lmax, off, 64));
    if (lane == 0) red[wave] = lmax;
    __syncthreads();
    lmax = fmaxf(fmaxf(red[0], red[1]), fmaxf(red[2], red[3]));

    float esum = 0.f, lsum = 0.f;
    for (int r = tid; r < NLOG; r += 256) {
        const float l = row[r];
        esum += __expf(l - lmax);
        if (r > 0) lsum += l;
    }
    #pragma unroll
    for (int off = 32; off; off >>= 1) {
        esum += __shfl_xor(esum, off, 64);
        lsum += __shfl_xor(lsum, off, 64);
    }
    if (lane == 0) { red2[wave][0] = esum; red2[wave][1] = lsum; }
    __syncthreads();

    if (tid == 0) {
        esum = red2[0][0] + red2[1][0] + red2[2][0] + red2[3][0];
        lsum = red2[0][1] + red2[1][1] + red2[2][1] + red2[3][1];
        const float lse  = lmax + logf(esum);
        const float l0   = row[0];
        const float loss = -0.9f * (l0 - lse)
                         - (0.1f / 512.f) * (lsum - 512.f * lse);
        loss_per_token[n] = loss;
    }
}

__global__ __launch_bounds__(256) void reduce_mean_kernel(
    const float* __restrict__ x, float* __restrict__ out, int n)
{
    const int tid = threadIdx.x;
    float s = 0.f;
    for (int i = tid; i < n; i += 256) s += x[i];
    #pragma unroll
    for (int off = 32; off; off >>= 1) s += __shfl_xor(s, off, 64);
    __shared__ float red[4];
    if ((tid & 63) == 0) red[tid >> 6] = s;
    __syncthreads();
    if (tid == 0) out[0] = (red[0] + red[1] + red[2] + red[3]) / (float)n;
}

// ------------------------- legacy fallback (R1) ----------------------------
__global__ __launch_bounds__(512) void nce_token_kernel(
    const float* __restrict__ h, const float* __restrict__ W,
    const int* __restrict__ target, const int* __restrict__ noise,
    float* __restrict__ loss_per_token)
{
    const int n    = blockIdx.x;
    const int tid  = threadIdx.x;
    const int lane = tid & 63;
    const int wave = tid >> 6;

    __shared__ float  logits[NLOG];
    __shared__ float4 hsm[HDIM / 4];
    __shared__ float  red[8];
    __shared__ float  red2[8][2];

    const float4* hrow = reinterpret_cast<const float4*>(h + (size_t)n * HDIM);
    if (tid < HDIM / 4) hsm[tid] = hrow[tid];
    __syncthreads();

    const float4 h0 = hsm[lane];
    const float4 h1 = hsm[lane + 64];
    const float4 h2 = hsm[lane + 128];
    const int* nrow = noise + (size_t)n * NSAMP;

    for (int r = wave; r < NLOG; r += 8) {
        const int row = (r == 0) ? target[n] : nrow[r - 1];
        const float4* wr = reinterpret_cast<const float4*>(W + (size_t)row * HDIM);
        const float4 w0 = wr[lane];
        const float4 w1 = wr[lane + 64];
        const float4 w2 = wr[lane + 128];
        float s;
        s  = h0.x * w0.x + h0.y * w0.y + h0.z * w0.z + h0.w * w0.w;
        s += h1.x * w1.x + h1.y * w1.y + h1.z * w1.z + h1.w * w1.w;
        s += h2.x * w2.x + h2.y * w2.y + h2.z * w2.z + h2.w * w2.w;
        #pragma unroll
        for (int off = 32; off; off >>= 1) s += __shfl_xor(s, off, 64);
        if (lane == 0) logits[r] = s;
    }
    __syncthreads();

    float lmax = -INFINITY;
    for (int r = tid; r < NLOG; r += 512) lmax = fmaxf(lmax, logits[r]);
    #pragma unroll
    for (int off = 32; off; off >>= 1) lmax = fmaxf(lmax, __shfl_xor(lmax, off, 64));
    if (lane == 0) red[wave] = lmax;
    __syncthreads();
    if (wave == 0) {
        float m = (lane < 8) ? red[lane] : -INFINITY;
        #pragma unroll
        for (int off = 4; off; off >>= 1) m = fmaxf(m, __shfl_xor(m, off, 64));
        if (lane == 0) red[0] = m;
    }
    __syncthreads();
    lmax = red[0];

    float esum = 0.f, lsum = 0.f;
    for (int r = tid; r < NLOG; r += 512) {
        const float l = logits[r];
        esum += __expf(l - lmax);
        if (r > 0) lsum += l;
    }
    #pragma unroll
    for (int off = 32; off; off >>= 1) {
        esum += __shfl_xor(esum, off, 64);
        lsum += __shfl_xor(lsum, off, 64);
    }
    if (lane == 0) { red2[wave][0] = esum; red2[wave][1] = lsum; }
    __syncthreads();

    if (tid == 0) {
        esum = 0.f; lsum = 0.f;
        #pragma unroll
        for (int w = 0; w < 8; ++w) { esum += red2[w][0]; lsum += red2[w][1]; }
        const float lse  = lmax + logf(esum);
        const float loss = -0.9f * (logits[0] - lse)
                         - (0.1f / 512.f) * (lsum - 512.f * lse);
        loss_per_token[n] = loss;
    }
}
// ---------------------------------------------------------------------------

extern "C" void kernel_launch(void* const* d_in, const int* in_sizes, int n_in,
                              void* d_out, int out_size, void* d_ws, size_t ws_size,
                              hipStream_t stream)
{
    const float* h      = (const float*)d_in[0];   // [N, 768] fp32
    const float* W      = (const float*)d_in[1];   // [50257, 768] fp32
    const int*   target = (const int*)d_in[2];     // [N] int32
    const int*   noise  = (const int*)d_in[3];     // [N, 512] int32
    float*       out    = (float*)d_out;
    const int    N      = in_sizes[2];             // 1024 tokens
    const int    nocc   = N * NLOG;                // 525312

    // ws layout (u32/f32 elements): counts[PADV] cursor[PADV] pay[nocc]
    //                               logits[nocc] loss[N]
    unsigned int* counts     = (unsigned int*)d_ws;
    unsigned int* cursor     = counts + PADV;
    unsigned int* sorted_pay = cursor + PADV;
    float*        logits     = (float*)(sorted_pay + nocc);
    float*        loss       = logits + nocc;
    const size_t  need_bytes = (size_t)(2 * PADV + 2 * nocc + N) * 4;

    if (ws_size < need_bytes) {
        // fallback: direct gather path (R1)
        float* ws = (float*)d_ws;
        nce_token_kernel<<<N, 512, 0, stream>>>(h, W, target, noise, ws);
        reduce_mean_kernel<<<1, 256, 0, stream>>>(ws, out, N);
        return;
    }

    hipMemsetAsync(counts, 0, (size_t)PADV * 4, stream);
    hist_kernel<<<512, 256, 0, stream>>>(target, noise, counts, N);
    scan_kernel<<<1, 1024, 0, stream>>>(counts, cursor);
    scatter_kernel<<<512, 256, 0, stream>>>(target, noise, cursor, sorted_pay, N);
    const int gblocks = (VOCAB + (GTPB / 64) - 1) / (GTPB / 64);
    gather_run_kernel<<<gblocks, GTPB, 0, stream>>>(h, W, counts, cursor,
                                                    sorted_pay, logits);
    softmax_loss_kernel<<<N, 256, 0, stream>>>(logits, loss);
    reduce_mean_kernel<<<1, 256, 0, stream>>>(loss, out, N);
}

// Round 6
// 153.246 us; speedup vs baseline: 2.9400x; 1.1682x over previous
//
#include <hip/hip_runtime.h>
#include <math.h>

#define HDIM   768
#define NSAMP  512
#define NLOG   513            // 1 target + 512 noise
#define VOCAB  50257
#define PADV   53248          // 1024 * 52, padded bin count for uint4 scan

// ---------------------------------------------------------------------------
// Sorted run-gather pipeline, bf16-h edition:
//  A) memsetAsync counts = 0 ; h -> packed bf16 (RTN) in ws
//  B) histogram of all 525312 vocab indices (int4 loads, global atomics)
//  C) single-block exclusive scan over padded bins (uint4 in/out) -> cursor
//  D) scatter: counting sort, payload only (tok<<10 | slot)
//  E) gather-run: ONE WAVE PER VOCAB RUN. W row (fp32) in registers for the
//     whole run; h rows read as packed bf16 (1.5KB/row, halves L1/L2 bytes);
//     2-occurrence software pipeline hides DS-swizzle reduce latency.
//  F) per-token log-softmax + smoothed loss
//  G) deterministic mean
// ---------------------------------------------------------------------------

// pack two f32 -> one u32 of two bf16 (round-to-nearest-even)
__device__ __forceinline__ unsigned int bf16rn(float x)
{
    unsigned int u = __float_as_uint(x);
    return (u + 0x7fffu + ((u >> 16) & 1u)) >> 16;
}

__global__ __launch_bounds__(256) void h_to_bf16_kernel(
    const float* __restrict__ h, unsigned int* __restrict__ hb, int n2)
{
    const int i = blockIdx.x * 256 + threadIdx.x;
    if (i >= n2) return;
    const float2 p = reinterpret_cast<const float2*>(h)[i];
    hb[i] = bf16rn(p.x) | (bf16rn(p.y) << 16);
}

__device__ __forceinline__ float blo(unsigned int u) { return __uint_as_float(u << 16); }
__device__ __forceinline__ float bhi(unsigned int u) { return __uint_as_float(u & 0xffff0000u); }

__global__ __launch_bounds__(256) void hist_kernel(
    const int* __restrict__ target, const int* __restrict__ noise,
    unsigned int* __restrict__ counts, int N)
{
    int i = blockIdx.x * 256 + threadIdx.x;
    int stride = gridDim.x * 256;
    const int nn4 = (N * NSAMP) / 4;
    const int4* noise4 = reinterpret_cast<const int4*>(noise);
    for (int k = i; k < nn4; k += stride) {
        const int4 v = noise4[k];
        atomicAdd(&counts[v.x], 1u);
        atomicAdd(&counts[v.y], 1u);
        atomicAdd(&counts[v.z], 1u);
        atomicAdd(&counts[v.w], 1u);
    }
    for (int k = i; k < N; k += stride) atomicAdd(&counts[target[k]], 1u);
}

// single block, 1024 threads, 52 bins/thread, uint4 I/O (counts padded+zeroed)
__global__ __launch_bounds__(1024) void scan_kernel(
    const unsigned int* __restrict__ counts, unsigned int* __restrict__ cursor)
{
    const int tid = threadIdx.x;
    const uint4* c4 = reinterpret_cast<const uint4*>(counts) + tid * 13;
    uint4*      o4 = reinterpret_cast<uint4*>(cursor) + tid * 13;

    __shared__ unsigned int lds[1024];
    unsigned int s = 0;
    #pragma unroll
    for (int i = 0; i < 13; ++i) {
        const uint4 c = c4[i];
        s += c.x + c.y + c.z + c.w;
    }
    lds[tid] = s;
    __syncthreads();
    #pragma unroll
    for (int off = 1; off < 1024; off <<= 1) {
        unsigned int t = (tid >= off) ? lds[tid - off] : 0u;
        __syncthreads();
        lds[tid] += t;
        __syncthreads();
    }
    unsigned int run = (tid > 0) ? lds[tid - 1] : 0u;   // exclusive prefix
    #pragma unroll
    for (int i = 0; i < 13; ++i) {
        const uint4 c = c4[i];
        uint4 o;
        o.x = run;
        o.y = o.x + c.x;
        o.z = o.y + c.y;
        o.w = o.z + c.z;
        run = o.w + c.w;
        o4[i] = o;
    }
}

__global__ __launch_bounds__(256) void scatter_kernel(
    const int* __restrict__ target, const int* __restrict__ noise,
    unsigned int* __restrict__ cursor,
    unsigned int* __restrict__ sorted_pay, int N)
{
    int i = blockIdx.x * 256 + threadIdx.x;
    int stride = gridDim.x * 256;
    const int nn4 = (N * NSAMP) / 4;
    const int4* noise4 = reinterpret_cast<const int4*>(noise);
    for (int k = i; k < nn4; k += stride) {
        const int4 vv = noise4[k];
        const int kk = k * 4;
        #pragma unroll
        for (int j = 0; j < 4; ++j) {
            const int v    = (j == 0) ? vv.x : (j == 1) ? vv.y : (j == 2) ? vv.z : vv.w;
            const int idx  = kk + j;
            const int tok  = idx >> 9;            // /512
            const int slot = (idx & 511) + 1;     // noise -> slots 1..512
            const unsigned int pos = atomicAdd(&cursor[v], 1u);
            sorted_pay[pos] = ((unsigned int)tok << 10) | (unsigned int)slot;
        }
    }
    for (int k = i; k < N; k += stride) {
        const int v = target[k];
        const unsigned int pos = atomicAdd(&cursor[v], 1u);
        sorted_pay[pos] = ((unsigned int)k << 10);   // slot 0
    }
}

// one wave per vocab run, 2-occurrence software pipeline, bf16 h rows
#define GTPB 256
__global__ __launch_bounds__(GTPB) void gather_run_kernel(
    const unsigned int* __restrict__ hb,          // packed bf16 h, 384 u32/row
    const float* __restrict__ W,
    const unsigned int* __restrict__ counts,
    const unsigned int* __restrict__ cursor,      // end offsets after scatter
    const unsigned int* __restrict__ sorted_pay,
    float* __restrict__ logits)
{
    const int v = blockIdx.x * (GTPB / 64) + (threadIdx.x >> 6);
    if (v >= VOCAB) return;
    const int cnt = (int)counts[v];
    if (cnt == 0) return;
    const int start = (int)cursor[v] - cnt;
    const int lane  = threadIdx.x & 63;

    // W row (fp32) resident in registers for the whole run.
    // Element map per lane: w0,w1 cover elems [8*lane, 8*lane+8),
    // w2 covers elems [512 + 4*lane, 512 + 4*lane + 4).
    const float4* wr = reinterpret_cast<const float4*>(W + (size_t)v * HDIM);
    const float4 w0 = wr[2 * lane];
    const float4 w1 = wr[2 * lane + 1];
    const float4 w2 = wr[128 + lane];

    const unsigned int* sp = sorted_pay + start;

    // prologue: load pair 0 (clamped)
    unsigned int pay0 = sp[0];
    unsigned int pay1 = sp[(cnt > 1) ? 1 : 0];
    const unsigned int* r0 = hb + (size_t)(pay0 >> 10) * (HDIM / 2);
    const unsigned int* r1 = hb + (size_t)(pay1 >> 10) * (HDIM / 2);
    uint4 x0 = reinterpret_cast<const uint4*>(r0)[lane];
    uint2 y0 = reinterpret_cast<const uint2*>(r0 + 256)[lane];
    uint4 x1 = reinterpret_cast<const uint4*>(r1)[lane];
    uint2 y1 = reinterpret_cast<const uint2*>(r1 + 256)[lane];

    for (int j = 0; j < cnt; j += 2) {
        // prefetch pair j+2 (clamped)
        const int i2 = (j + 2 < cnt) ? j + 2 : cnt - 1;
        const int i3 = (j + 3 < cnt) ? j + 3 : cnt - 1;
        const unsigned int npay0 = sp[i2];
        const unsigned int npay1 = sp[i3];
        const unsigned int* nr0 = hb + (size_t)(npay0 >> 10) * (HDIM / 2);
        const unsigned int* nr1 = hb + (size_t)(npay1 >> 10) * (HDIM / 2);
        const uint4 nx0 = reinterpret_cast<const uint4*>(nr0)[lane];
        const uint2 ny0 = reinterpret_cast<const uint2*>(nr0 + 256)[lane];
        const uint4 nx1 = reinterpret_cast<const uint4*>(nr1)[lane];
        const uint2 ny1 = reinterpret_cast<const uint2*>(nr1 + 256)[lane];

        // two independent dot products
        float s0, s1;
        s0  = blo(x0.x) * w0.x + bhi(x0.x) * w0.y + blo(x0.y) * w0.z + bhi(x0.y) * w0.w;
        s1  = blo(x1.x) * w0.x + bhi(x1.x) * w0.y + blo(x1.y) * w0.z + bhi(x1.y) * w0.w;
        s0 += blo(x0.z) * w1.x + bhi(x0.z) * w1.y + blo(x0.w) * w1.z + bhi(x0.w) * w1.w;
        s1 += blo(x1.z) * w1.x + bhi(x1.z) * w1.y + blo(x1.w) * w1.z + bhi(x1.w) * w1.w;
        s0 += blo(y0.x) * w2.x + bhi(y0.x) * w2.y + blo(y0.y) * w2.z + bhi(y0.y) * w2.w;
        s1 += blo(y1.x) * w2.x + bhi(y1.x) * w2.y + blo(y1.y) * w2.z + bhi(y1.y) * w2.w;

        // interleaved shuffle reductions (two independent chains)
        #pragma unroll
        for (int off = 32; off; off >>= 1) {
            s0 += __shfl_xor(s0, off, 64);
            s1 += __shfl_xor(s1, off, 64);
        }
        if (lane == 0) {
            logits[(size_t)(pay0 >> 10) * NLOG + (pay0 & 1023u)] = s0;
            if (j + 1 < cnt)
                logits[(size_t)(pay1 >> 10) * NLOG + (pay1 & 1023u)] = s1;
        }
        pay0 = npay0; pay1 = npay1;
        x0 = nx0; y0 = ny0; x1 = nx1; y1 = ny1;
    }
}

__global__ __launch_bounds__(256) void softmax_loss_kernel(
    const float* __restrict__ logits, float* __restrict__ loss_per_token)
{
    const int n    = blockIdx.x;
    const int tid  = threadIdx.x;
    const int lane = tid & 63;
    const int wave = tid >> 6;
    const float* row = logits + (size_t)n * NLOG;

    __shared__ float red[4];
    __shared__ float red2[4][2];

    float lmax = -INFINITY;
    for (int r = tid; r < NLOG; r += 256) lmax = fmaxf(lmax, row[r]);
    #pragma unroll
    for (int off = 32; off; off >>= 1) lmax = fmaxf(lmax, __shfl_xor(lmax, off, 64));
    if (lane == 0) red[wave] = lmax;
    __syncthreads();
    lmax = fmaxf(fmaxf(red[0], red[1]), fmaxf(red[2], red[3]));

    float esum = 0.f, lsum = 0.f;
    for (int r = tid; r < NLOG; r += 256) {
        const float l = row[r];
        esum += __expf(l - lmax);
        if (r > 0) lsum += l;
    }
    #pragma unroll
    for (int off = 32; off; off >>= 1) {
        esum += __shfl_xor(esum, off, 64);
        lsum += __shfl_xor(lsum, off, 64);
    }
    if (lane == 0) { red2[wave][0] = esum; red2[wave][1] = lsum; }
    __syncthreads();

    if (tid == 0) {
        esum = red2[0][0] + red2[1][0] + red2[2][0] + red2[3][0];
        lsum = red2[0][1] + red2[1][1] + red2[2][1] + red2[3][1];
        const float lse  = lmax + logf(esum);
        const float l0   = row[0];
        const float loss = -0.9f * (l0 - lse)
                         - (0.1f / 512.f) * (lsum - 512.f * lse);
        loss_per_token[n] = loss;
    }
}

__global__ __launch_bounds__(256) void reduce_mean_kernel(
    const float* __restrict__ x, float* __restrict__ out, int n)
{
    const int tid = threadIdx.x;
    float s = 0.f;
    for (int i = tid; i < n; i += 256) s += x[i];
    #pragma unroll
    for (int off = 32; off; off >>= 1) s += __shfl_xor(s, off, 64);
    __shared__ float red[4];
    if ((tid & 63) == 0) red[tid >> 6] = s;
    __syncthreads();
    if (tid == 0) out[0] = (red[0] + red[1] + red[2] + red[3]) / (float)n;
}

// ------------------------- legacy fallback (R1) ----------------------------
__global__ __launch_bounds__(512) void nce_token_kernel(
    const float* __restrict__ h, const float* __restrict__ W,
    const int* __restrict__ target, const int* __restrict__ noise,
    float* __restrict__ loss_per_token)
{
    const int n    = blockIdx.x;
    const int tid  = threadIdx.x;
    const int lane = tid & 63;
    const int wave = tid >> 6;

    __shared__ float  logits[NLOG];
    __shared__ float4 hsm[HDIM / 4];
    __shared__ float  red[8];
    __shared__ float  red2[8][2];

    const float4* hrow = reinterpret_cast<const float4*>(h + (size_t)n * HDIM);
    if (tid < HDIM / 4) hsm[tid] = hrow[tid];
    __syncthreads();

    const float4 h0 = hsm[lane];
    const float4 h1 = hsm[lane + 64];
    const float4 h2 = hsm[lane + 128];
    const int* nrow = noise + (size_t)n * NSAMP;

    for (int r = wave; r < NLOG; r += 8) {
        const int row = (r == 0) ? target[n] : nrow[r - 1];
        const float4* wr = reinterpret_cast<const float4*>(W + (size_t)row * HDIM);
        const float4 w0 = wr[lane];
        const float4 w1 = wr[lane + 64];
        const float4 w2 = wr[lane + 128];
        float s;
        s  = h0.x * w0.x + h0.y * w0.y + h0.z * w0.z + h0.w * w0.w;
        s += h1.x * w1.x + h1.y * w1.y + h1.z * w1.z + h1.w * w1.w;
        s += h2.x * w2.x + h2.y * w2.y + h2.z * w2.z + h2.w * w2.w;
        #pragma unroll
        for (int off = 32; off; off >>= 1) s += __shfl_xor(s, off, 64);
        if (lane == 0) logits[r] = s;
    }
    __syncthreads();

    float lmax = -INFINITY;
    for (int r = tid; r < NLOG; r += 512) lmax = fmaxf(lmax, logits[r]);
    #pragma unroll
    for (int off = 32; off; off >>= 1) lmax = fmaxf(lmax, __shfl_xor(lmax, off, 64));
    if (lane == 0) red[wave] = lmax;
    __syncthreads();
    if (wave == 0) {
        float m = (lane < 8) ? red[lane] : -INFINITY;
        #pragma unroll
        for (int off = 4; off; off >>= 1) m = fmaxf(m, __shfl_xor(m, off, 64));
        if (lane == 0) red[0] = m;
    }
    __syncthreads();
    lmax = red[0];

    float esum = 0.f, lsum = 0.f;
    for (int r = tid; r < NLOG; r += 512) {
        const float l = logits[r];
        esum += __expf(l - lmax);
        if (r > 0) lsum += l;
    }
    #pragma unroll
    for (int off = 32; off; off >>= 1) {
        esum += __shfl_xor(esum, off, 64);
        lsum += __shfl_xor(lsum, off, 64);
    }
    if (lane == 0) { red2[wave][0] = esum; red2[wave][1] = lsum; }
    __syncthreads();

    if (tid == 0) {
        esum = 0.f; lsum = 0.f;
        #pragma unroll
        for (int w = 0; w < 8; ++w) { esum += red2[w][0]; lsum += red2[w][1]; }
        const float lse  = lmax + logf(esum);
        const float loss = -0.9f * (logits[0] - lse)
                         - (0.1f / 512.f) * (lsum - 512.f * lse);
        loss_per_token[n] = loss;
    }
}
// ---------------------------------------------------------------------------

extern "C" void kernel_launch(void* const* d_in, const int* in_sizes, int n_in,
                              void* d_out, int out_size, void* d_ws, size_t ws_size,
                              hipStream_t stream)
{
    const float* h      = (const float*)d_in[0];   // [N, 768] fp32
    const float* W      = (const float*)d_in[1];   // [50257, 768] fp32
    const int*   target = (const int*)d_in[2];     // [N] int32
    const int*   noise  = (const int*)d_in[3];     // [N, 512] int32
    float*       out    = (float*)d_out;
    const int    N      = in_sizes[2];             // 1024 tokens
    const int    nocc   = N * NLOG;                // 525312
    const int    nh2    = N * HDIM / 2;            // 393216 packed u32

    // ws layout (u32/f32 elements): counts[PADV] cursor[PADV] pay[nocc]
    //                               hb[nh2] logits[nocc] loss[N]
    unsigned int* counts     = (unsigned int*)d_ws;
    unsigned int* cursor     = counts + PADV;
    unsigned int* sorted_pay = cursor + PADV;
    unsigned int* hb         = sorted_pay + nocc;
    float*        logits     = (float*)(hb + nh2);
    float*        loss       = logits + nocc;
    const size_t  need_bytes = (size_t)(2 * PADV + 2 * nocc + nh2 + N) * 4;

    if (ws_size < need_bytes) {
        // fallback: direct gather path (R1)
        float* ws = (float*)d_ws;
        nce_token_kernel<<<N, 512, 0, stream>>>(h, W, target, noise, ws);
        reduce_mean_kernel<<<1, 256, 0, stream>>>(ws, out, N);
        return;
    }

    hipMemsetAsync(counts, 0, (size_t)PADV * 4, stream);
    h_to_bf16_kernel<<<(nh2 + 255) / 256, 256, 0, stream>>>(h, hb, nh2);
    hist_kernel<<<512, 256, 0, stream>>>(target, noise, counts, N);
    scan_kernel<<<1, 1024, 0, stream>>>(counts, cursor);
    scatter_kernel<<<512, 256, 0, stream>>>(target, noise, cursor, sorted_pay, N);
    const int gblocks = (VOCAB + (GTPB / 64) - 1) / (GTPB / 64);
    gather_run_kernel<<<gblocks, GTPB, 0, stream>>>(hb, W, counts, cursor,
                                                    sorted_pay, logits);
    softmax_loss_kernel<<<N, 256, 0, stream>>>(logits, loss);
    reduce_mean_kernel<<<1, 256, 0, stream>>>(loss, out, N);
}